// Round 1
// baseline (471.864 us; speedup 1.0000x reference)
//
#include <hip/hip_runtime.h>
#include <hip/hip_cooperative_groups.h>
#include <math.h>

namespace cg = cooperative_groups;

#define C_DIM 256
#define HW_DIM 1024
#define N_DIM 64
#define M_TOTAL (N_DIM * HW_DIM)   // 65536
#define EPS_F 1e-5f

typedef __attribute__((ext_vector_type(8))) short short8;   // 8 bf16 (MFMA A/B frag)
typedef __attribute__((ext_vector_type(4))) float v4f;      // MFMA C/D frag

// fp32 -> bf16 round-to-nearest-even
__device__ __forceinline__ unsigned short f2bf(float x) {
    unsigned u = __float_as_uint(x);
    u = (u + 0x7FFFu + ((u >> 16) & 1u)) >> 16;
    return (unsigned short)u;
}
__device__ __forceinline__ float bf2f(unsigned short h) {
    return __uint_as_float(((unsigned)h) << 16);
}
__device__ __forceinline__ unsigned pack2(float lo, float hi) {
    return (unsigned)f2bf(lo) | ((unsigned)f2bf(hi) << 16);
}
// split float4 into hi (bf16 RNE) and lo (bf16 of residual): ~fp32 precision in 2 bf16
__device__ __forceinline__ void split4(float4 v, uint2* hi, uint2* lo) {
    unsigned short h0 = f2bf(v.x), h1 = f2bf(v.y), h2 = f2bf(v.z), h3 = f2bf(v.w);
    float r0 = v.x - bf2f(h0), r1 = v.y - bf2f(h1), r2 = v.z - bf2f(h2), r3 = v.w - bf2f(h3);
    hi->x = (unsigned)h0 | ((unsigned)h1 << 16);
    hi->y = (unsigned)h2 | ((unsigned)h3 << 16);
    lo->x = (unsigned)f2bf(r0) | ((unsigned)f2bf(r1) << 16);
    lo->y = (unsigned)f2bf(r2) | ((unsigned)f2bf(r3) << 16);
}

// ---------------------------------------------------------------------------
// Kernel 1: Xbf = bf16(X) + per-channel sums (atomic). grid 4096, block 256.
__global__ void prepass_kernel(const float* __restrict__ X, unsigned short* __restrict__ Xbf,
                               float* __restrict__ musum) {
    int b = blockIdx.x;
    int t = threadIdx.x;
    int r = t >> 6;
    int l = t & 63;
    size_t row = (size_t)(4 * b + r);
    const float4* src = (const float4*)(X + (row << 10));
    uint2* dst = (uint2*)(Xbf + (row << 10));
    float s = 0.f;
#pragma unroll
    for (int j = 0; j < 4; ++j) {
        float4 v = src[l + 64 * j];
        uint2 p; p.x = pack2(v.x, v.y); p.y = pack2(v.z, v.w);
        dst[l + 64 * j] = p;
        s += v.x + v.y + v.z + v.w;
    }
    for (int off = 32; off > 0; off >>= 1) s += __shfl_down(s, off);
    if (l == 0) atomicAdd(&musum[(4 * b + r) & 255], s);
}

// ---------------------------------------------------------------------------
// Kernel 2: raw Gram G += X X^T via bf16 MFMA, symmetric (3 unique tiles).
// grid (3 tiles, 128 k-splits), block 512 (8 waves: 2x4 of 64x32).
__global__ __launch_bounds__(512, 3)
void gram_mfma(const unsigned short* __restrict__ Xbf, float* __restrict__ G) {
    int tile = blockIdx.x;               // 0:(0,0) 1:(0,128) 2:(128,128)
    int ci = (tile >> 1) * 128;
    int cj = (tile == 0) ? 0 : 128;
    int ks = blockIdx.y;                 // 0..127, K=512 each
    int t = threadIdx.x, wave = t >> 6, lane = t & 63;
    int wy = wave >> 2, wx = wave & 3;
    int quad = lane >> 4, l16 = lane & 15;

    __shared__ __align__(16) unsigned short As[128 * 72];
    __shared__ __align__(16) unsigned short Bs[128 * 72];
    const unsigned short* Bsrc = (ci == cj) ? As : Bs;

    v4f acc[4][2] = {};
    int n = ks >> 1;
    int hwbase = (ks & 1) * 512;
    const unsigned short* base = Xbf + (((size_t)n * C_DIM) << 10);
    int srow = t >> 2;
    int schunk = t & 3;

    for (int s = 0; s < 8; ++s) {
        int k0 = hwbase + s * 64;
        __syncthreads();
#pragma unroll
        for (int h = 0; h < 2; ++h) {
            int ch = schunk + 4 * h;
            *(uint4*)&As[srow * 72 + ch * 8] =
                *(const uint4*)&base[(((size_t)(ci + srow)) << 10) + k0 + ch * 8];
            if (ci != cj)
                *(uint4*)&Bs[srow * 72 + ch * 8] =
                    *(const uint4*)&base[(((size_t)(cj + srow)) << 10) + k0 + ch * 8];
        }
        __syncthreads();

        short8 af[4][2], bfr[2][2];
#pragma unroll
        for (int mt = 0; mt < 4; ++mt)
#pragma unroll
            for (int kh = 0; kh < 2; ++kh)
                af[mt][kh] = *(const short8*)&As[(64 * wy + 16 * mt + l16) * 72 + kh * 32 + quad * 8];
#pragma unroll
        for (int nt = 0; nt < 2; ++nt)
#pragma unroll
            for (int kh = 0; kh < 2; ++kh)
                bfr[nt][kh] = *(const short8*)&Bsrc[(32 * wx + 16 * nt + l16) * 72 + kh * 32 + quad * 8];
#pragma unroll
        for (int kh = 0; kh < 2; ++kh)
#pragma unroll
            for (int mt = 0; mt < 4; ++mt)
#pragma unroll
                for (int nt = 0; nt < 2; ++nt)
                    acc[mt][nt] = __builtin_amdgcn_mfma_f32_16x16x32_bf16(af[mt][kh], bfr[nt][kh], acc[mt][nt], 0, 0, 0);
    }

#pragma unroll
    for (int mt = 0; mt < 4; ++mt)
#pragma unroll
        for (int nt = 0; nt < 2; ++nt)
#pragma unroll
            for (int r = 0; r < 4; ++r) {
                int row = ci + 64 * wy + 16 * mt + 4 * quad + r;
                int col = cj + 32 * wx + 16 * nt + l16;
                atomicAdd(&G[row * C_DIM + col], acc[mt][nt][r]);
            }
}

// ---------------------------------------------------------------------------
// MFMA 64x64-tile matmul core, K=256, bf16 hi/lo split (~fp32 precision).
// REQUIRES: B symmetric (stages B rows as columns). block 256 (4 waves 2x2).
// Fills acc[2][2] (wave covers 32x32; mt,nt over 16x16 MFMA tiles).
__device__ __forceinline__ void mm_mfma64(const float* __restrict__ A, const float* __restrict__ B,
                                          int ci, int cj, v4f acc[2][2],
                                          unsigned short* Ah, unsigned short* Al,
                                          unsigned short* Bh, unsigned short* Bl) {
    int t = threadIdx.x, wave = t >> 6, lane = t & 63;
    int wy = wave >> 1, wx = wave & 1;
    int quad = lane >> 4, l16 = lane & 15;
    int row = t >> 2, cg_ = (t & 3) * 16;

    for (int kb = 0; kb < 256; kb += 64) {
        __syncthreads();
#pragma unroll
        for (int i = 0; i < 4; ++i) {
            float4 va = *(const float4*)&A[(ci + row) * C_DIM + kb + cg_ + 4 * i];
            uint2 hi, lo;
            split4(va, &hi, &lo);
            *(uint2*)&Ah[row * 72 + cg_ + 4 * i] = hi;
            *(uint2*)&Al[row * 72 + cg_ + 4 * i] = lo;
            float4 vb = *(const float4*)&B[(cj + row) * C_DIM + kb + cg_ + 4 * i];
            split4(vb, &hi, &lo);
            *(uint2*)&Bh[row * 72 + cg_ + 4 * i] = hi;
            *(uint2*)&Bl[row * 72 + cg_ + 4 * i] = lo;
        }
        __syncthreads();

        short8 fah[2][2], fal[2][2], fbh[2][2], fbl[2][2];
#pragma unroll
        for (int mt = 0; mt < 2; ++mt)
#pragma unroll
            for (int kh = 0; kh < 2; ++kh) {
                int off = (32 * wy + 16 * mt + l16) * 72 + kh * 32 + quad * 8;
                fah[mt][kh] = *(const short8*)&Ah[off];
                fal[mt][kh] = *(const short8*)&Al[off];
            }
#pragma unroll
        for (int nt = 0; nt < 2; ++nt)
#pragma unroll
            for (int kh = 0; kh < 2; ++kh) {
                int off = (32 * wx + 16 * nt + l16) * 72 + kh * 32 + quad * 8;
                fbh[nt][kh] = *(const short8*)&Bh[off];
                fbl[nt][kh] = *(const short8*)&Bl[off];
            }
#pragma unroll
        for (int kh = 0; kh < 2; ++kh)
#pragma unroll
            for (int mt = 0; mt < 2; ++mt)
#pragma unroll
                for (int nt = 0; nt < 2; ++nt) {
                    acc[mt][nt] = __builtin_amdgcn_mfma_f32_16x16x32_bf16(fah[mt][kh], fbh[nt][kh], acc[mt][nt], 0, 0, 0);
                    acc[mt][nt] = __builtin_amdgcn_mfma_f32_16x16x32_bf16(fah[mt][kh], fbl[nt][kh], acc[mt][nt], 0, 0, 0);
                    acc[mt][nt] = __builtin_amdgcn_mfma_f32_16x16x32_bf16(fal[mt][kh], fbh[nt][kh], acc[mt][nt], 0, 0, 0);
                }
    }
}

// ---------------------------------------------------------------------------
// Fused cooperative kernel: scal + init + 9 NS iterations + rot.
// grid 32 blocks x 256 threads (trivially co-resident on 256 CUs).
// Phase A (all 32 blocks): T1 = P@P (bid<16), T2 = P@Sig (bid>=16).
// Phase B (16 blocks):     P  = 1.5P - 0.5*T1@T2.
// 19 grid.sync()s replace 20 kernel launches.
__global__ __launch_bounds__(256, 1)
void ns_fused(const float* __restrict__ G, const float* __restrict__ musum,
              const float* __restrict__ R,
              float* __restrict__ Sig, float* __restrict__ P,
              float* __restrict__ T1, float* __restrict__ T2,
              unsigned short* __restrict__ Mbf, float* __restrict__ moff) {
    cg::grid_group grid = cg::this_grid();

    __shared__ __align__(16) unsigned short Ah[64 * 72];
    __shared__ __align__(16) unsigned short Al[64 * 72];
    __shared__ __align__(16) unsigned short Bh[64 * 72];
    __shared__ __align__(16) unsigned short Bl[64 * 72];
    __shared__ float red[256];
    __shared__ float scal_sh[2];

    int bid = blockIdx.x;
    int t = threadIdx.x;
    int wave = t >> 6, lane = t & 63;
    int wy = wave >> 1, wx = wave & 1, quad = lane >> 4, l16 = lane & 15;

    // ---- Phase 0: trace of Sigma (every block computes identical trr, no global round-trip)
    {
        float mu = musum[t] * (1.0f / M_TOTAL);
        float d = G[t * (C_DIM + 1)] * (1.0f / M_TOTAL) - mu * mu + EPS_F;
        red[t] = d;
        __syncthreads();
        for (int off = 128; off > 0; off >>= 1) {
            if (t < off) red[t] += red[t + off];
            __syncthreads();
        }
        if (t == 0) {
            float trr = 1.0f / red[0];
            scal_sh[0] = trr;
            scal_sh[1] = sqrtf(trr);
        }
        __syncthreads();
    }
    float trr = scal_sh[0];
    float s1  = scal_sh[1];

    // ---- Phase 1: Sig = Sigma_N (mirrored symmetric), P = 1.5I - 0.5*Sig. 2048 elems/block.
    {
        int base = bid * 2048 + t;
#pragma unroll
        for (int j = 0; j < 8; ++j) {
            int idx = base + j * 256;
            int r = idx >> 8, c = idx & 255;
            float g = (r >= 128 && c < 128) ? G[c * C_DIM + r] : G[idx];
            float mu_r = musum[r] * (1.0f / M_TOTAL);
            float mu_c = musum[c] * (1.0f / M_TOTAL);
            float sig = (g * (1.0f / M_TOTAL) - mu_r * mu_c + ((r == c) ? EPS_F : 0.f)) * trr;
            Sig[idx] = sig;
            P[idx] = ((r == c) ? 1.5f : 0.f) - 0.5f * sig;
        }
    }
    grid.sync();

    // ---- Phase 2: 9 Newton-Schulz iterations
    for (int it = 1; it < 10; ++it) {
        {   // A: 32 blocks, two independent matmuls
            int tb = bid & 15;
            int ci = (tb >> 2) * 64, cj = (tb & 3) * 64;
            const float* B = (bid < 16) ? P : Sig;
            float* D = (bid < 16) ? T1 : T2;
            v4f acc[2][2] = {};
            mm_mfma64(P, B, ci, cj, acc, Ah, Al, Bh, Bl);
#pragma unroll
            for (int mt = 0; mt < 2; ++mt)
#pragma unroll
                for (int nt = 0; nt < 2; ++nt)
#pragma unroll
                    for (int r = 0; r < 4; ++r) {
                        int rr = ci + 32 * wy + 16 * mt + 4 * quad + r;
                        int cc = cj + 32 * wx + 16 * nt + l16;
                        D[rr * C_DIM + cc] = acc[mt][nt][r];
                    }
        }
        grid.sync();
        if (bid < 16) {  // B: P = 1.5P - 0.5*(T1@T2)   (T2 symmetric: P,Sig commute)
            int ci = (bid >> 2) * 64, cj = (bid & 3) * 64;
            v4f acc[2][2] = {};
            mm_mfma64(T1, T2, ci, cj, acc, Ah, Al, Bh, Bl);
#pragma unroll
            for (int mt = 0; mt < 2; ++mt)
#pragma unroll
                for (int nt = 0; nt < 2; ++nt)
#pragma unroll
                    for (int r = 0; r < 4; ++r) {
                        int rr = ci + 32 * wy + 16 * mt + 4 * quad + r;
                        int cc = cj + 32 * wx + 16 * nt + l16;
                        int idx = rr * C_DIM + cc;
                        P[idx] = 1.5f * P[idx] - 0.5f * acc[mt][nt][r];
                    }
        }
        grid.sync();
    }

    // ---- Phase 3: rot. M = (R@P)*s1 -> Mbf (bf16) + moff[d] = dot(M[d,:], mu).
    if (bid < 16) {
        int ci = (bid >> 2) * 64, cj = (bid & 3) * 64;
        v4f acc[2][2] = {};
        mm_mfma64(R, P, ci, cj, acc, Ah, Al, Bh, Bl);

        float muc[2];
#pragma unroll
        for (int nt = 0; nt < 2; ++nt)
            muc[nt] = musum[cj + 32 * wx + 16 * nt + l16] * (1.0f / M_TOTAL);
#pragma unroll
        for (int mt = 0; mt < 2; ++mt)
#pragma unroll
            for (int r = 0; r < 4; ++r) {
                int rr = ci + 32 * wy + 16 * mt + 4 * quad + r;
                float s = 0.f;
#pragma unroll
                for (int nt = 0; nt < 2; ++nt) {
                    float val = acc[mt][nt][r] * s1;
                    Mbf[rr * C_DIM + cj + 32 * wx + 16 * nt + l16] = f2bf(val);
                    s += val * muc[nt];
                }
                s += __shfl_xor(s, 1); s += __shfl_xor(s, 2);
                s += __shfl_xor(s, 4); s += __shfl_xor(s, 8);
                if (l16 == 0) atomicAdd(&moff[rr], s);
            }
    }
}

// ---------------------------------------------------------------------------
// Kernel 6: out[n,d,hw] = sum_c Mbf[d,c]*Xbf[n,c,hw] - moff[d]  via MFMA.
// grid: (8 hw-tiles, 2 d-tiles, 64 n), block 256 (4 waves of 64x64).
// Epilogue: LDS transpose -> float4 coalesced stores (full 128B lines).
__global__ void out_mfma(const unsigned short* __restrict__ Xbf,
                         const unsigned short* __restrict__ Mbf,
                         const float* __restrict__ moff, float* __restrict__ out) {
    int hwb = blockIdx.x * 128;
    int db  = blockIdx.y * 128;
    int n   = blockIdx.z;
    int t = threadIdx.x, wave = t >> 6, lane = t & 63;
    int wy = wave >> 1, wx = wave & 1, quad = lane >> 4, l16 = lane & 15;

    __shared__ __align__(16) unsigned short Asm[128 * 40];
    __shared__ __align__(16) unsigned short Bsm[128 * 34];
    __shared__ __align__(16) float Ep[4 * 16 * 68];   // per-wave 16x64 epilogue buffer

    v4f acc[4][4] = {};
    const unsigned short* Xn = Xbf + (((size_t)n * C_DIM) << 10);

    for (int kb = 0; kb < 256; kb += 32) {
        __syncthreads();
#pragma unroll
        for (int i = 0; i < 2; ++i) {
            int a = t + 256 * i;
            int row = a >> 2, c8 = a & 3;
            *(uint4*)(&Asm[row * 40 + 8 * c8]) =
                *(const uint4*)(&Mbf[(db + row) * C_DIM + kb + 8 * c8]);
        }
#pragma unroll
        for (int i = 0; i < 16; ++i) {
            int idx = t + 256 * i;
            int hw = idx & 127, crow = idx >> 7;
            Bsm[hw * 34 + crow] = Xn[(((size_t)(kb + crow)) << 10) + hwb + hw];
        }
        __syncthreads();

        short8 af[4], bfr[4];
#pragma unroll
        for (int mt = 0; mt < 4; ++mt)
            af[mt] = *(const short8*)(&Asm[(64 * wy + 16 * mt + l16) * 40 + 8 * quad]);
#pragma unroll
        for (int nt = 0; nt < 4; ++nt) {
            union { short8 s; unsigned u[4]; } tmp;
            const unsigned short* bp = &Bsm[(64 * wx + 16 * nt + l16) * 34 + 8 * quad];
            tmp.u[0] = *(const unsigned*)(bp + 0);
            tmp.u[1] = *(const unsigned*)(bp + 2);
            tmp.u[2] = *(const unsigned*)(bp + 4);
            tmp.u[3] = *(const unsigned*)(bp + 6);
            bfr[nt] = tmp.s;
        }
#pragma unroll
        for (int mt = 0; mt < 4; ++mt)
#pragma unroll
            for (int nt = 0; nt < 4; ++nt)
                acc[mt][nt] = __builtin_amdgcn_mfma_f32_16x16x32_bf16(af[mt], bfr[nt], acc[mt][nt], 0, 0, 0);
    }

    float* W = &Ep[wave * 16 * 68];
#pragma unroll
    for (int mt = 0; mt < 4; ++mt) {
        // dump this wave's 16x64 tile (row = 4*quad+r, col = 16*nt+l16), moff folded in
#pragma unroll
        for (int r = 0; r < 4; ++r) {
            float off = moff[db + 64 * wy + 16 * mt + 4 * quad + r];
#pragma unroll
            for (int nt = 0; nt < 4; ++nt)
                W[(4 * quad + r) * 68 + 16 * nt + l16] = acc[mt][nt][r] - off;
        }
        __syncthreads();   // orders wave-local LDS ops; uniform across block
        // read back transposed-in-lane: 16 lanes x float4 = 256B contiguous per row
#pragma unroll
        for (int j = 0; j < 4; ++j) {
            int row = 4 * j + quad;
            float4 v = *(const float4*)&W[row * 68 + 4 * l16];
            int d = db + 64 * wy + 16 * mt + row;
            int hw = hwb + 64 * wx + 4 * l16;
            *(float4*)&out[(((size_t)(n * C_DIM + d)) << 10) + hw] = v;
        }
        __syncthreads();
    }
}

// ---------------------------------------------------------------------------
extern "C" void kernel_launch(void* const* d_in, const int* in_sizes, int n_in,
                              void* d_out, int out_size, void* d_ws, size_t ws_size,
                              hipStream_t stream) {
    const float* X = (const float*)d_in[0];        // (64,256,32,32)
    const float* R = (const float*)d_in[1];        // (1,256,256)
    float* out = (float*)d_out;
    float* ws  = (float*)d_ws;

    float* musum = ws;                         // 256
    // ws+256..271: (was scal, now unused — kept for layout stability)
    float* moff  = ws + 272;                   // 256
    float* G     = ws + 528;                   // 65536 (raw gram, 3 tiles)
    float* Sig   = G + 65536;                  // Sigma_N fp32 (symmetric)
    float* P     = Sig + 65536;
    float* T1    = P + 65536;
    float* T2    = T1 + 65536;
    unsigned short* Mbf = (unsigned short*)(T2 + 65536);   // 65536 ushort
    unsigned short* Xbf = Mbf + 65536;                     // 16M ushort (32 MB)

    hipMemsetAsync(ws, 0, (528 + 65536) * sizeof(float), stream);

    prepass_kernel<<<4096, 256, 0, stream>>>(X, Xbf, musum);
    gram_mfma<<<dim3(3, 128), 512, 0, stream>>>(Xbf, G);

    {
        const float* Gc = G;
        const float* musumc = musum;
        const float* Rc = R;
        void* args[] = {(void*)&Gc, (void*)&musumc, (void*)&Rc,
                        (void*)&Sig, (void*)&P, (void*)&T1, (void*)&T2,
                        (void*)&Mbf, (void*)&moff};
        hipLaunchCooperativeKernel((void*)ns_fused, dim3(32), dim3(256),
                                   args, 0, stream);
    }

    out_mfma<<<dim3(8, 2, 64), 256, 0, stream>>>(Xbf, Mbf, moff, out);
}

// Round 2
// 410.201 us; speedup vs baseline: 1.1503x; 1.1503x over previous
//
#include <hip/hip_runtime.h>
#include <math.h>

#define C_DIM 256
#define HW_DIM 1024
#define N_DIM 64
#define M_TOTAL (N_DIM * HW_DIM)   // 65536
#define EPS_F 1e-5f

typedef __attribute__((ext_vector_type(8))) short short8;   // 8 bf16 (MFMA A/B frag)
typedef __attribute__((ext_vector_type(4))) float v4f;      // MFMA C/D frag

// fp32 -> bf16 round-to-nearest-even
__device__ __forceinline__ unsigned short f2bf(float x) {
    unsigned u = __float_as_uint(x);
    u = (u + 0x7FFFu + ((u >> 16) & 1u)) >> 16;
    return (unsigned short)u;
}
__device__ __forceinline__ float bf2f(unsigned short h) {
    return __uint_as_float(((unsigned)h) << 16);
}
__device__ __forceinline__ unsigned pack2(float lo, float hi) {
    return (unsigned)f2bf(lo) | ((unsigned)f2bf(hi) << 16);
}
// split float4 into hi (bf16 RNE) and lo (bf16 of residual): ~fp32 precision in 2 bf16
__device__ __forceinline__ void split4(float4 v, uint2* hi, uint2* lo) {
    unsigned short h0 = f2bf(v.x), h1 = f2bf(v.y), h2 = f2bf(v.z), h3 = f2bf(v.w);
    float r0 = v.x - bf2f(h0), r1 = v.y - bf2f(h1), r2 = v.z - bf2f(h2), r3 = v.w - bf2f(h3);
    hi->x = (unsigned)h0 | ((unsigned)h1 << 16);
    hi->y = (unsigned)h2 | ((unsigned)h3 << 16);
    lo->x = (unsigned)f2bf(r0) | ((unsigned)f2bf(r1) << 16);
    lo->y = (unsigned)f2bf(r2) | ((unsigned)f2bf(r3) << 16);
}

// ---------------------------------------------------------------------------
// Lightweight grid barrier: monotonic counter at LLC, agent-scope.
// All 32 blocks must be co-resident (regular launch, 32 blocks on 256 CUs).
// Release: each wave drains vmcnt at __syncthreads; thread0's __threadfence()
// writes back this XCD's L2. Acquire: after spin, __threadfence() invalidates
// L1/L2 before the exit __syncthreads releases the block's loads.
__device__ __forceinline__ void gsync(unsigned* bar, unsigned target) {
    __syncthreads();
    if (threadIdx.x == 0) {
        __threadfence();
        __hip_atomic_fetch_add(bar, 1u, __ATOMIC_RELAXED, __HIP_MEMORY_SCOPE_AGENT);
        while (__hip_atomic_load(bar, __ATOMIC_RELAXED, __HIP_MEMORY_SCOPE_AGENT) < target) {
            __builtin_amdgcn_s_sleep(1);
        }
        __threadfence();
    }
    __syncthreads();
}

// ---------------------------------------------------------------------------
// Kernel 1: Xbf = bf16(X) + per-channel sums (atomic). grid 4096, block 256.
__global__ void prepass_kernel(const float* __restrict__ X, unsigned short* __restrict__ Xbf,
                               float* __restrict__ musum) {
    int b = blockIdx.x;
    int t = threadIdx.x;
    int r = t >> 6;
    int l = t & 63;
    size_t row = (size_t)(4 * b + r);
    const float4* src = (const float4*)(X + (row << 10));
    uint2* dst = (uint2*)(Xbf + (row << 10));
    float s = 0.f;
#pragma unroll
    for (int j = 0; j < 4; ++j) {
        float4 v = src[l + 64 * j];
        uint2 p; p.x = pack2(v.x, v.y); p.y = pack2(v.z, v.w);
        dst[l + 64 * j] = p;
        s += v.x + v.y + v.z + v.w;
    }
    for (int off = 32; off > 0; off >>= 1) s += __shfl_down(s, off);
    if (l == 0) atomicAdd(&musum[(4 * b + r) & 255], s);
}

// ---------------------------------------------------------------------------
// Kernel 2: raw Gram G += X X^T via bf16 MFMA, symmetric (3 unique tiles).
// grid (3 tiles, 128 k-splits), block 512 (8 waves: 2x4 of 64x32).
__global__ __launch_bounds__(512, 3)
void gram_mfma(const unsigned short* __restrict__ Xbf, float* __restrict__ G) {
    int tile = blockIdx.x;               // 0:(0,0) 1:(0,128) 2:(128,128)
    int ci = (tile >> 1) * 128;
    int cj = (tile == 0) ? 0 : 128;
    int ks = blockIdx.y;                 // 0..127, K=512 each
    int t = threadIdx.x, wave = t >> 6, lane = t & 63;
    int wy = wave >> 2, wx = wave & 3;
    int quad = lane >> 4, l16 = lane & 15;

    __shared__ __align__(16) unsigned short As[128 * 72];
    __shared__ __align__(16) unsigned short Bs[128 * 72];
    const unsigned short* Bsrc = (ci == cj) ? As : Bs;

    v4f acc[4][2] = {};
    int n = ks >> 1;
    int hwbase = (ks & 1) * 512;
    const unsigned short* base = Xbf + (((size_t)n * C_DIM) << 10);
    int srow = t >> 2;
    int schunk = t & 3;

    for (int s = 0; s < 8; ++s) {
        int k0 = hwbase + s * 64;
        __syncthreads();
#pragma unroll
        for (int h = 0; h < 2; ++h) {
            int ch = schunk + 4 * h;
            *(uint4*)&As[srow * 72 + ch * 8] =
                *(const uint4*)&base[(((size_t)(ci + srow)) << 10) + k0 + ch * 8];
            if (ci != cj)
                *(uint4*)&Bs[srow * 72 + ch * 8] =
                    *(const uint4*)&base[(((size_t)(cj + srow)) << 10) + k0 + ch * 8];
        }
        __syncthreads();

        short8 af[4][2], bfr[2][2];
#pragma unroll
        for (int mt = 0; mt < 4; ++mt)
#pragma unroll
            for (int kh = 0; kh < 2; ++kh)
                af[mt][kh] = *(const short8*)&As[(64 * wy + 16 * mt + l16) * 72 + kh * 32 + quad * 8];
#pragma unroll
        for (int nt = 0; nt < 2; ++nt)
#pragma unroll
            for (int kh = 0; kh < 2; ++kh)
                bfr[nt][kh] = *(const short8*)&Bsrc[(32 * wx + 16 * nt + l16) * 72 + kh * 32 + quad * 8];
#pragma unroll
        for (int kh = 0; kh < 2; ++kh)
#pragma unroll
            for (int mt = 0; mt < 4; ++mt)
#pragma unroll
                for (int nt = 0; nt < 2; ++nt)
                    acc[mt][nt] = __builtin_amdgcn_mfma_f32_16x16x32_bf16(af[mt][kh], bfr[nt][kh], acc[mt][nt], 0, 0, 0);
    }

#pragma unroll
    for (int mt = 0; mt < 4; ++mt)
#pragma unroll
        for (int nt = 0; nt < 2; ++nt)
#pragma unroll
            for (int r = 0; r < 4; ++r) {
                int row = ci + 64 * wy + 16 * mt + 4 * quad + r;
                int col = cj + 32 * wx + 16 * nt + l16;
                atomicAdd(&G[row * C_DIM + col], acc[mt][nt][r]);
            }
}

// ---------------------------------------------------------------------------
// MFMA 64x64-tile matmul core, K=256, bf16 hi/lo split (~fp32 precision).
// REQUIRES: B symmetric (stages B rows as columns). block 256 (4 waves 2x2).
// Software-pipelined: next K-chunk global loads issue before current MFMAs.
__device__ __forceinline__ void mm_mfma64(const float* __restrict__ A, const float* __restrict__ B,
                                          int ci, int cj, v4f acc[2][2],
                                          unsigned short* Ah, unsigned short* Al,
                                          unsigned short* Bh, unsigned short* Bl) {
    int t = threadIdx.x, wave = t >> 6, lane = t & 63;
    int wy = wave >> 1, wx = wave & 1;
    int quad = lane >> 4, l16 = lane & 15;
    int row = t >> 2, cg_ = (t & 3) * 16;

    float4 va[4], vb[4];
#pragma unroll
    for (int i = 0; i < 4; ++i) {
        va[i] = *(const float4*)&A[(ci + row) * C_DIM + cg_ + 4 * i];
        vb[i] = *(const float4*)&B[(cj + row) * C_DIM + cg_ + 4 * i];
    }

    for (int kb = 0; kb < 256; kb += 64) {
        __syncthreads();
#pragma unroll
        for (int i = 0; i < 4; ++i) {
            uint2 hi, lo;
            split4(va[i], &hi, &lo);
            *(uint2*)&Ah[row * 72 + cg_ + 4 * i] = hi;
            *(uint2*)&Al[row * 72 + cg_ + 4 * i] = lo;
            split4(vb[i], &hi, &lo);
            *(uint2*)&Bh[row * 72 + cg_ + 4 * i] = hi;
            *(uint2*)&Bl[row * 72 + cg_ + 4 * i] = lo;
        }
        if (kb < 192) {
#pragma unroll
            for (int i = 0; i < 4; ++i) {
                va[i] = *(const float4*)&A[(ci + row) * C_DIM + kb + 64 + cg_ + 4 * i];
                vb[i] = *(const float4*)&B[(cj + row) * C_DIM + kb + 64 + cg_ + 4 * i];
            }
        }
        __syncthreads();

        short8 fah[2][2], fal[2][2], fbh[2][2], fbl[2][2];
#pragma unroll
        for (int mt = 0; mt < 2; ++mt)
#pragma unroll
            for (int kh = 0; kh < 2; ++kh) {
                int off = (32 * wy + 16 * mt + l16) * 72 + kh * 32 + quad * 8;
                fah[mt][kh] = *(const short8*)&Ah[off];
                fal[mt][kh] = *(const short8*)&Al[off];
            }
#pragma unroll
        for (int nt = 0; nt < 2; ++nt)
#pragma unroll
            for (int kh = 0; kh < 2; ++kh) {
                int off = (32 * wx + 16 * nt + l16) * 72 + kh * 32 + quad * 8;
                fbh[nt][kh] = *(const short8*)&Bh[off];
                fbl[nt][kh] = *(const short8*)&Bl[off];
            }
#pragma unroll
        for (int kh = 0; kh < 2; ++kh)
#pragma unroll
            for (int mt = 0; mt < 2; ++mt)
#pragma unroll
                for (int nt = 0; nt < 2; ++nt) {
                    acc[mt][nt] = __builtin_amdgcn_mfma_f32_16x16x32_bf16(fah[mt][kh], fbh[nt][kh], acc[mt][nt], 0, 0, 0);
                    acc[mt][nt] = __builtin_amdgcn_mfma_f32_16x16x32_bf16(fah[mt][kh], fbl[nt][kh], acc[mt][nt], 0, 0, 0);
                    acc[mt][nt] = __builtin_amdgcn_mfma_f32_16x16x32_bf16(fal[mt][kh], fbh[nt][kh], acc[mt][nt], 0, 0, 0);
                }
    }
}

// ---------------------------------------------------------------------------
// Persistent NS kernel: scal + init + 9 NS iterations + rot, custom barrier.
// REGULAR launch, 32 blocks x 256 threads (co-resident on 256 CUs).
// Phase A (32 blocks): T1 = P@P (bid<16), T2 = P@Sig (bid>=16).
// Phase B (16 blocks): P  = 1.5P - 0.5*T1@T2.
__global__ __launch_bounds__(256, 1)
void ns_persist(const float* __restrict__ G, const float* __restrict__ musum,
                const float* __restrict__ R,
                float* __restrict__ Sig, float* __restrict__ P,
                float* __restrict__ T1, float* __restrict__ T2,
                unsigned short* __restrict__ Mbf, float* __restrict__ moff,
                unsigned* __restrict__ bar) {
    __shared__ __align__(16) unsigned short Ah[64 * 72];
    __shared__ __align__(16) unsigned short Al[64 * 72];
    __shared__ __align__(16) unsigned short Bh[64 * 72];
    __shared__ __align__(16) unsigned short Bl[64 * 72];
    __shared__ float red[256];
    __shared__ float scal_sh[2];

    int bid = blockIdx.x;
    int t = threadIdx.x;
    int wave = t >> 6, lane = t & 63;
    int wy = wave >> 1, wx = wave & 1, quad = lane >> 4, l16 = lane & 15;
    unsigned tg = 0;

    // ---- Phase 0: trace of Sigma (every block computes identical trr)
    {
        float mu = musum[t] * (1.0f / M_TOTAL);
        float d = G[t * (C_DIM + 1)] * (1.0f / M_TOTAL) - mu * mu + EPS_F;
        red[t] = d;
        __syncthreads();
        for (int off = 128; off > 0; off >>= 1) {
            if (t < off) red[t] += red[t + off];
            __syncthreads();
        }
        if (t == 0) {
            float trr = 1.0f / red[0];
            scal_sh[0] = trr;
            scal_sh[1] = sqrtf(trr);
        }
        __syncthreads();
    }
    float trr = scal_sh[0];
    float s1  = scal_sh[1];

    // ---- Phase 1: Sig = Sigma_N (mirrored symmetric), P = 1.5I - 0.5*Sig.
    {
        int base = bid * 2048 + t;
#pragma unroll
        for (int j = 0; j < 8; ++j) {
            int idx = base + j * 256;
            int r = idx >> 8, c = idx & 255;
            float g = (r >= 128 && c < 128) ? G[c * C_DIM + r] : G[idx];
            float mu_r = musum[r] * (1.0f / M_TOTAL);
            float mu_c = musum[c] * (1.0f / M_TOTAL);
            float sig = (g * (1.0f / M_TOTAL) - mu_r * mu_c + ((r == c) ? EPS_F : 0.f)) * trr;
            Sig[idx] = sig;
            P[idx] = ((r == c) ? 1.5f : 0.f) - 0.5f * sig;
        }
    }
    tg += 32; gsync(bar, tg);

    // ---- Phase 2: 9 Newton-Schulz iterations
    for (int it = 1; it < 10; ++it) {
        {   // A: 32 blocks, two independent matmuls
            int tb = bid & 15;
            int ci = (tb >> 2) * 64, cj = (tb & 3) * 64;
            const float* B = (bid < 16) ? P : Sig;
            float* D = (bid < 16) ? T1 : T2;
            v4f acc[2][2] = {};
            mm_mfma64(P, B, ci, cj, acc, Ah, Al, Bh, Bl);
#pragma unroll
            for (int mt = 0; mt < 2; ++mt)
#pragma unroll
                for (int nt = 0; nt < 2; ++nt)
#pragma unroll
                    for (int r = 0; r < 4; ++r) {
                        int rr = ci + 32 * wy + 16 * mt + 4 * quad + r;
                        int cc = cj + 32 * wx + 16 * nt + l16;
                        D[rr * C_DIM + cc] = acc[mt][nt][r];
                    }
        }
        tg += 32; gsync(bar, tg);
        if (bid < 16) {  // B: P = 1.5P - 0.5*(T1@T2)   (T2 symmetric: P,Sig commute)
            int ci = (bid >> 2) * 64, cj = (bid & 3) * 64;
            v4f acc[2][2] = {};
            mm_mfma64(T1, T2, ci, cj, acc, Ah, Al, Bh, Bl);
#pragma unroll
            for (int mt = 0; mt < 2; ++mt)
#pragma unroll
                for (int nt = 0; nt < 2; ++nt)
#pragma unroll
                    for (int r = 0; r < 4; ++r) {
                        int rr = ci + 32 * wy + 16 * mt + 4 * quad + r;
                        int cc = cj + 32 * wx + 16 * nt + l16;
                        int idx = rr * C_DIM + cc;
                        P[idx] = 1.5f * P[idx] - 0.5f * acc[mt][nt][r];
                    }
        }
        tg += 32; gsync(bar, tg);
    }

    // ---- Phase 3: rot. M = (R@P)*s1 -> Mbf (bf16) + moff[d] = dot(M[d,:], mu).
    if (bid < 16) {
        int ci = (bid >> 2) * 64, cj = (bid & 3) * 64;
        v4f acc[2][2] = {};
        mm_mfma64(R, P, ci, cj, acc, Ah, Al, Bh, Bl);

        float muc[2];
#pragma unroll
        for (int nt = 0; nt < 2; ++nt)
            muc[nt] = musum[cj + 32 * wx + 16 * nt + l16] * (1.0f / M_TOTAL);
#pragma unroll
        for (int mt = 0; mt < 2; ++mt)
#pragma unroll
            for (int r = 0; r < 4; ++r) {
                int rr = ci + 32 * wy + 16 * mt + 4 * quad + r;
                float s = 0.f;
#pragma unroll
                for (int nt = 0; nt < 2; ++nt) {
                    float val = acc[mt][nt][r] * s1;
                    Mbf[rr * C_DIM + cj + 32 * wx + 16 * nt + l16] = f2bf(val);
                    s += val * muc[nt];
                }
                s += __shfl_xor(s, 1); s += __shfl_xor(s, 2);
                s += __shfl_xor(s, 4); s += __shfl_xor(s, 8);
                if (l16 == 0) atomicAdd(&moff[rr], s);
            }
    }
}

// ---------------------------------------------------------------------------
// Kernel 6: out[n,d,hw] = sum_c Mbf[d,c]*Xbf[n,c,hw] - moff[d]  via MFMA.
// grid: (8 hw-tiles, 2 d-tiles, 64 n), block 256 (4 waves of 64x64).
// Epilogue: LDS transpose -> float4 coalesced stores (full 128B lines).
__global__ void out_mfma(const unsigned short* __restrict__ Xbf,
                         const unsigned short* __restrict__ Mbf,
                         const float* __restrict__ moff, float* __restrict__ out) {
    int hwb = blockIdx.x * 128;
    int db  = blockIdx.y * 128;
    int n   = blockIdx.z;
    int t = threadIdx.x, wave = t >> 6, lane = t & 63;
    int wy = wave >> 1, wx = wave & 1, quad = lane >> 4, l16 = lane & 15;

    __shared__ __align__(16) unsigned short Asm[128 * 40];
    __shared__ __align__(16) unsigned short Bsm[128 * 34];
    __shared__ __align__(16) float Ep[4 * 16 * 68];   // per-wave 16x64 epilogue buffer

    v4f acc[4][4] = {};
    const unsigned short* Xn = Xbf + (((size_t)n * C_DIM) << 10);

    for (int kb = 0; kb < 256; kb += 32) {
        __syncthreads();
#pragma unroll
        for (int i = 0; i < 2; ++i) {
            int a = t + 256 * i;
            int row = a >> 2, c8 = a & 3;
            *(uint4*)(&Asm[row * 40 + 8 * c8]) =
                *(const uint4*)(&Mbf[(db + row) * C_DIM + kb + 8 * c8]);
        }
#pragma unroll
        for (int i = 0; i < 16; ++i) {
            int idx = t + 256 * i;
            int hw = idx & 127, crow = idx >> 7;
            Bsm[hw * 34 + crow] = Xn[(((size_t)(kb + crow)) << 10) + hwb + hw];
        }
        __syncthreads();

        short8 af[4], bfr[4];
#pragma unroll
        for (int mt = 0; mt < 4; ++mt)
            af[mt] = *(const short8*)(&Asm[(64 * wy + 16 * mt + l16) * 40 + 8 * quad]);
#pragma unroll
        for (int nt = 0; nt < 4; ++nt) {
            union { short8 s; unsigned u[4]; } tmp;
            const unsigned short* bp = &Bsm[(64 * wx + 16 * nt + l16) * 34 + 8 * quad];
            tmp.u[0] = *(const unsigned*)(bp + 0);
            tmp.u[1] = *(const unsigned*)(bp + 2);
            tmp.u[2] = *(const unsigned*)(bp + 4);
            tmp.u[3] = *(const unsigned*)(bp + 6);
            bfr[nt] = tmp.s;
        }
#pragma unroll
        for (int mt = 0; mt < 4; ++mt)
#pragma unroll
            for (int nt = 0; nt < 4; ++nt)
                acc[mt][nt] = __builtin_amdgcn_mfma_f32_16x16x32_bf16(af[mt], bfr[nt], acc[mt][nt], 0, 0, 0);
    }

    float* W = &Ep[wave * 16 * 68];
#pragma unroll
    for (int mt = 0; mt < 4; ++mt) {
        // dump this wave's 16x64 tile (row = 4*quad+r, col = 16*nt+l16), moff folded in
#pragma unroll
        for (int r = 0; r < 4; ++r) {
            float off = moff[db + 64 * wy + 16 * mt + 4 * quad + r];
#pragma unroll
            for (int nt = 0; nt < 4; ++nt)
                W[(4 * quad + r) * 68 + 16 * nt + l16] = acc[mt][nt][r] - off;
        }
        __syncthreads();   // orders wave-local LDS ops; uniform across block
        // read back transposed-in-lane: 16 lanes x float4 = 256B contiguous per row
#pragma unroll
        for (int j = 0; j < 4; ++j) {
            int row = 4 * j + quad;
            float4 v = *(const float4*)&W[row * 68 + 4 * l16];
            int d = db + 64 * wy + 16 * mt + row;
            int hw = hwb + 64 * wx + 4 * l16;
            *(float4*)&out[(((size_t)(n * C_DIM + d)) << 10) + hw] = v;
        }
        __syncthreads();
    }
}

// ---------------------------------------------------------------------------
extern "C" void kernel_launch(void* const* d_in, const int* in_sizes, int n_in,
                              void* d_out, int out_size, void* d_ws, size_t ws_size,
                              hipStream_t stream) {
    const float* X = (const float*)d_in[0];        // (64,256,32,32)
    const float* R = (const float*)d_in[1];        // (1,256,256)
    float* out = (float*)d_out;
    float* ws  = (float*)d_ws;

    float* musum = ws;                         // 256
    unsigned* bar = (unsigned*)(ws + 256);     // barrier counter (zeroed by memset)
    float* moff  = ws + 272;                   // 256
    float* G     = ws + 528;                   // 65536 (raw gram, 3 tiles)
    float* Sig   = G + 65536;                  // Sigma_N fp32 (symmetric)
    float* P     = Sig + 65536;
    float* T1    = P + 65536;
    float* T2    = T1 + 65536;
    unsigned short* Mbf = (unsigned short*)(T2 + 65536);   // 65536 ushort
    unsigned short* Xbf = Mbf + 65536;                     // 16M ushort (32 MB)

    hipMemsetAsync(ws, 0, (528 + 65536) * sizeof(float), stream);

    prepass_kernel<<<4096, 256, 0, stream>>>(X, Xbf, musum);
    gram_mfma<<<dim3(3, 128), 512, 0, stream>>>(Xbf, G);

    ns_persist<<<32, 256, 0, stream>>>(G, musum, R, Sig, P, T1, T2, Mbf, moff, bar);

    out_mfma<<<dim3(8, 2, 64), 256, 0, stream>>>(Xbf, Mbf, moff, out);
}